// Round 7
// baseline (234.563 us; speedup 1.0000x reference)
//
#include <hip/hip_runtime.h>
#include <math.h>

// DTW 2048x2048, squared-diff cost, out = sqrt(DTW[2047][2047]).
//
// Round-7: TLP. NW=8 waves (512 thr) on one CU = 2 waves/SIMD, R=4 rows/lane.
// Rounds 5/6 showed a ~140cy/step floor with 1 wave/SIMD regardless of
// intra-wave ILP -- dependent-VALU stalls can't be filled from within the
// wave. Two co-resident waves per SIMD fill each other's stall slots
// (independent streams, m114 co-scheduling).
//
// Dataflow = round-5 (validated): lane l of wave w owns rows 4*(64w+l)..+3;
// at wave-step t computes column j = t - l (skew-1). Per 64-step block: two
// coalesced ds_read_b32 (y[tau0+lane], ring slot (tau0+lane)&255); per step
// v_readlane(blk, s) yields wave-uniform scalars injected into two DPP
// wave_shr:1 conveyors (yconv = y[t-l]; u = lane l-1's row-3 value, lane 0
// takes the ring injection). Nothing for the compiler to sink to LDS.
//
// Ring rows are WRAPPED mod 256 (9 rows x 1KB; unwrapped would be 78KB).
// Within an epoch, producer writes cols (consumer_tau0+65..+191) while the
// consumer reads cols (tau0..tau0+63): distance in [2,191], never 0 mod 256
// -> no collision. Col j+256 overwrites slot j&255 at global step >= j+128+
// (>= 2 barrier epochs after the consumer's read). Lane 63 (true strip
// boundary) writes each col last (step j+63) and the consumer reads it at
// global >= j+65, in a later barrier epoch. All round-5 invariants hold.
//
// Guard-free: INFV=1e30 absorbs adds (1e30 + d^2 == 1e30 in fp32); OOB-col
// garbage stays confined to OOB cells/slots (proof as round 5). One unified
// body for tau0 in [0,2048]; output at (w=7, lane=63, tau0=2048, s=62).

#define NLEN  2048
#define NW    8
#define CSTEP 64
#define DSKEW 128
#define RB    256            // wrapped ring slots per row (power of 2)
#define GTOT  3008           // (NW-1)*DSKEW + 2048 + 64
#define INFV  1e30f

__device__ __forceinline__ float dpp_shr1(float v, float inj) {
    int r = __builtin_amdgcn_update_dpp(
        __builtin_bit_cast(int, inj), __builtin_bit_cast(int, v),
        0x138 /*wave_shr:1*/, 0xF, 0xF, false /*lane0 takes old=inj*/);
    return __builtin_bit_cast(float, r);
}
__device__ __forceinline__ float rdlane(float v, int l) {
    return __builtin_bit_cast(float,
        __builtin_amdgcn_readlane(__builtin_bit_cast(int, v), l));
}
__device__ __forceinline__ float min3f(float a, float b, float c) {
    return fminf(fminf(a, b), c);
}

__global__ __launch_bounds__(512, 1) void dtw_kernel(const float* __restrict__ X,
                                                     const float* __restrict__ Y,
                                                     float* __restrict__ out) {
    __shared__ __align__(16) float yS[NLEN];
    __shared__ float ring[(NW + 1) * RB];   // row 0 = virtual row -1 (INF)

    const int tid  = threadIdx.x;
    const int w    = tid >> 6;
    const int lane = tid & 63;

    {   // y: 512 threads x float4 = 2048
        ((float4*)yS)[tid] = ((const float4*)Y)[tid];
    }
    for (int k = tid; k < (NW + 1) * RB; k += 512) ring[k] = INFV;
    __syncthreads();

    // rows tid*4 .. tid*4+3
    float x0, x1, x2, x3;
    {
        const float4 xa = *(const float4*)&X[tid * 4];
        x0 = xa.x; x1 = xa.y; x2 = xa.z; x3 = xa.w;
    }

    float v0 = INFV, v1 = INFV, v2 = INFV, v3 = INFV;
    float uprev = (tid == 0) ? 0.0f : INFV;   // DTW[-1][-1]=0 seed
    float yconv = 0.0f;                       // y DPP conveyor

    const float* ringR = ring + w * RB;
    float*       ringW = ring + (w + 1) * RB;

    for (int gb = 0; gb < GTOT; gb += CSTEP) {
        const int tau0 = gb - w * DSKEW;

        if (tau0 >= 0 && tau0 <= NLEN) {
            int yi = tau0 + lane;                   // OOB cols only at 2048
            if (yi > NLEN - 1) yi = NLEN - 1;
            const float yblk = yS[yi];                                // ds_read
            const float rblk = ringR[(unsigned)(tau0 + lane) & (RB - 1u)]; // ds_read
            const int   wb   = tau0 - lane;         // write col base
            const bool  isout = (tau0 == NLEN) & (w == NW - 1) & (lane == 63);

            #pragma unroll
            for (int s = 0; s < CSTEP; ++s) {
                const float yu = rdlane(yblk, s);   // y[tau0+s]
                const float ru = rdlane(rblk, s);   // ring col tau0+s
                yconv = dpp_shr1(yconv, yu);        // lane l: y[tau0+s-l]
                const float u = dpp_shr1(v3, ru);   // lane l-1's row-3 value
                float d0 = x0 - yconv; float nv0 = fmaf(d0, d0, min3f(v0, uprev, u));
                float d1 = x1 - yconv; float nv1 = fmaf(d1, d1, min3f(v1, v0, nv0));
                float d2 = x2 - yconv; float nv2 = fmaf(d2, d2, min3f(v2, v1, nv1));
                float d3 = x3 - yconv; float nv3 = fmaf(d3, d3, min3f(v3, v2, nv2));
                ringW[(unsigned)(wb + s) & (RB - 1u)] = nv3;
                uprev = u;
                v0 = nv0; v1 = nv1; v2 = nv2; v3 = nv3;
                if (s == 62 && isout) out[0] = sqrtf(nv3);   // col 2047
            }
        }
        __syncthreads();
    }
}

extern "C" void kernel_launch(void* const* d_in, const int* in_sizes, int n_in,
                              void* d_out, int out_size, void* d_ws, size_t ws_size,
                              hipStream_t stream) {
    const float* x = (const float*)d_in[0];
    const float* y = (const float*)d_in[1];
    (void)in_sizes; (void)n_in; (void)out_size; (void)d_ws; (void)ws_size;
    dtw_kernel<<<1, 512, 0, stream>>>(x, y, (float*)d_out);
}

// Round 8
// 207.333 us; speedup vs baseline: 1.1313x; 1.1313x over previous
//
#include <hip/hip_runtime.h>
#include <math.h>

// DTW 2048x2048, squared-diff cost, out = sqrt(DTW[2047][2047]).
//
// Round-8: C=2 columns per step. R5/R6/R7 all hit ~145 cy/step regardless
// of per-step organization (ILP, TLP, instr count) -> amortize the per-step
// wall over 2x cells and halve the step count.
//
// NW=4 waves (256 thr), R=8 rows/lane, lane l of wave w owns rows
// 8*(64w+l)..+7. At wave-step tau, lane l computes cols c0=2(tau-l), c1=c0+1
// for its 8 rows: 16 cells/step. Steps: 1376 (vs 2496 at C=1).
//
// Delivery (R5-proven): per 32-step block, two coalesced ds_read_b32
// (y[2*tau0+lane], ring[2*tau0+lane] -- 64 cols each); per step,
// v_readlane(blk, 2s / 2s+1) yields wave-uniform scalars injected into four
// DPP wave_shr:1 conveyors:
//   yA/yB: y[c0], y[c1]
//   u0 = dpp(p7a, r0): lane l-1's row-7 col-c0 value (lane 0: ring col c0)
//   u1 = dpp(v7,  r1): lane l-1's row-7 col-c1 value (lane 0: ring col c1)
// where p7a = previous step's nva[7], v7 = previous step's nvb[7].
//
// Recurrence per row r (left state v[r] = row r value at col c0-1):
//   col c0: nva[r] = d^2 + min3(v[r],  diagA, upA),
//           upA = r? nva[r-1] : u0,  diagA = r? v[r-1]  : uprev1
//   col c1: nvb[r] = d^2 + min3(nva[r], diagB, upB),
//           upB = r? nvb[r-1] : u1,  diagB = r? nva[r-1] : u0
//   state: v[r] = nvb[r]; uprev1 = u1; p7a = nva[7].
//
// Ring: unwrapped rows (PAD=128 + 2176 slots), imm-offset ds_write_b64 of
// the adjacent pair (nva7, nvb7) -- no wrap arithmetic. 5 rows x 9216 B +
// 8 KB y = 54.3 KB LDS. SK=96 steps (192 cols), barrier every 32 steps:
// producer lane 63 writes col 2*tau0+63 at its step tau0+94, strictly
// before the consumer's block barrier at producer-step tau0+96.
//
// Guard-free: INFV=1e30 absorbs adds (1e30 + d^2 == 1e30 fp32); ramp-in
// cols<0 stay INF by induction (conveyors/pads init INF), ramp-out cols
// >=2048 produce garbage confined to OOB cells (DP flows right/down only).
// Seed DTW[-1][-1]=0 enters as uprev1 for tid 0. Output at the unique
// step (w=3, lane=63, tau0=1056, s=30) where c1==2047.

#define NLEN  2048
#define NW    4
#define CSTEP 32               // steps per barrier block (64 cols)
#define SK    96               // inter-wave skew in steps (> 94 required)
#define PAD   128
#define RROW  (PAD + 2176)     // 2304 floats per ring row
#define GTOT  1376             // last block: w=3 at tau0=1056
#define TAUMAX 1086            // last active wave-step (lane63 c1=2047)
#define INFV  1e30f

__device__ __forceinline__ float dpp_shr1(float v, float inj) {
    int r = __builtin_amdgcn_update_dpp(
        __builtin_bit_cast(int, inj), __builtin_bit_cast(int, v),
        0x138 /*wave_shr:1*/, 0xF, 0xF, false /*lane0 takes old=inj*/);
    return __builtin_bit_cast(float, r);
}
__device__ __forceinline__ float rdlane(float v, int l) {
    return __builtin_bit_cast(float,
        __builtin_amdgcn_readlane(__builtin_bit_cast(int, v), l));
}
__device__ __forceinline__ float min3f(float a, float b, float c) {
    return fminf(fminf(a, b), c);
}

__global__ __launch_bounds__(256, 1) void dtw_kernel(const float* __restrict__ X,
                                                     const float* __restrict__ Y,
                                                     float* __restrict__ out) {
    __shared__ __align__(16) float yS[NLEN];
    __shared__ __align__(16) float ring[(NW + 1) * RROW];

    const int tid  = threadIdx.x;
    const int w    = tid >> 6;
    const int lane = tid & 63;

    {
        const float4* Y4 = (const float4*)Y;
        float4* y4 = (float4*)yS;
        y4[tid]       = Y4[tid];
        y4[tid + 256] = Y4[tid + 256];
    }
    for (int k = tid; k < (NW + 1) * RROW; k += 256) ring[k] = INFV;
    __syncthreads();

    float x0, x1, x2, x3, x4, x5, x6, x7;
    {
        const float4 xa = *(const float4*)&X[tid * 8];
        const float4 xb = *(const float4*)&X[tid * 8 + 4];
        x0 = xa.x; x1 = xa.y; x2 = xa.z; x3 = xa.w;
        x4 = xb.x; x5 = xb.y; x6 = xb.z; x7 = xb.w;
    }

    float v0 = INFV, v1 = INFV, v2 = INFV, v3 = INFV;
    float v4 = INFV, v5 = INFV, v6 = INFV, v7 = INFV;
    float p7a   = INFV;                        // prev step's nva[7]
    float uprev1 = (tid == 0) ? 0.0f : INFV;   // prev step's u1 (DTW[-1][-1] seed)
    float yA = 0.0f, yB = 0.0f;                // y conveyors

    const float* ringR = ring + w * RROW + PAD;
    float*       ringW = ring + (w + 1) * RROW + PAD;

    for (int gb = 0; gb < GTOT; gb += CSTEP) {
        const int tau0 = gb - w * SK;

        if (tau0 >= 0 && tau0 <= TAUMAX) {
            int yi = 2 * tau0 + lane;
            if (yi > NLEN - 1) yi = NLEN - 1;          // OOB cols only
            const float yblk = yS[yi];                 // coalesced ds_read
            const float rblk = ringR[2 * tau0 + lane]; // coalesced ds_read
            float* wp = ringW + (2 * tau0 - 2 * lane);
            const bool isout = (tau0 == 1056) & (w == NW - 1) & (lane == 63);

            #pragma unroll
            for (int s = 0; s < CSTEP; ++s) {
                const float r0 = rdlane(rblk, 2 * s);
                const float r1 = rdlane(rblk, 2 * s + 1);
                const float y0 = rdlane(yblk, 2 * s);
                const float y1 = rdlane(yblk, 2 * s + 1);
                yA = dpp_shr1(yA, y0);            // y[c0]
                yB = dpp_shr1(yB, y1);            // y[c1]
                const float u0 = dpp_shr1(p7a, r0);   // up (row0, c0)
                const float u1 = dpp_shr1(v7,  r1);   // up (row0, c1)
                // ---- col c0 ----
                float dA, nva0, nva1, nva2, nva3, nva4, nva5, nva6, nva7;
                dA = x0 - yA; nva0 = fmaf(dA, dA, min3f(v0, uprev1, u0));
                dA = x1 - yA; nva1 = fmaf(dA, dA, min3f(v1, v0, nva0));
                dA = x2 - yA; nva2 = fmaf(dA, dA, min3f(v2, v1, nva1));
                dA = x3 - yA; nva3 = fmaf(dA, dA, min3f(v3, v2, nva2));
                dA = x4 - yA; nva4 = fmaf(dA, dA, min3f(v4, v3, nva3));
                dA = x5 - yA; nva5 = fmaf(dA, dA, min3f(v5, v4, nva4));
                dA = x6 - yA; nva6 = fmaf(dA, dA, min3f(v6, v5, nva5));
                dA = x7 - yA; nva7 = fmaf(dA, dA, min3f(v7, v6, nva6));
                // ---- col c1 ----
                float dB, nvb0, nvb1, nvb2, nvb3, nvb4, nvb5, nvb6, nvb7;
                dB = x0 - yB; nvb0 = fmaf(dB, dB, min3f(nva0, u0, u1));
                dB = x1 - yB; nvb1 = fmaf(dB, dB, min3f(nva1, nva0, nvb0));
                dB = x2 - yB; nvb2 = fmaf(dB, dB, min3f(nva2, nva1, nvb1));
                dB = x3 - yB; nvb3 = fmaf(dB, dB, min3f(nva3, nva2, nvb2));
                dB = x4 - yB; nvb4 = fmaf(dB, dB, min3f(nva4, nva3, nvb3));
                dB = x5 - yB; nvb5 = fmaf(dB, dB, min3f(nva5, nva4, nvb4));
                dB = x6 - yB; nvb6 = fmaf(dB, dB, min3f(nva6, nva5, nvb5));
                dB = x7 - yB; nvb7 = fmaf(dB, dB, min3f(nva7, nva6, nvb6));
                // bottom-row pair -> ring (ds_write_b64, imm offset)
                *(float2*)(wp + 2 * s) = make_float2(nva7, nvb7);
                // state
                p7a = nva7; uprev1 = u1;
                v0 = nvb0; v1 = nvb1; v2 = nvb2; v3 = nvb3;
                v4 = nvb4; v5 = nvb5; v6 = nvb6; v7 = nvb7;
                if (s == 30 && isout) out[0] = sqrtf(nvb7);   // c1 == 2047
            }
        }
        __syncthreads();
    }
}

extern "C" void kernel_launch(void* const* d_in, const int* in_sizes, int n_in,
                              void* d_out, int out_size, void* d_ws, size_t ws_size,
                              hipStream_t stream) {
    const float* x = (const float*)d_in[0];
    const float* y = (const float*)d_in[1];
    (void)in_sizes; (void)n_in; (void)out_size; (void)d_ws; (void)ws_size;
    dtw_kernel<<<1, 256, 0, stream>>>(x, y, (float*)d_out);
}